// Round 2
// baseline (607.637 us; speedup 1.0000x reference)
//
#include <hip/hip_runtime.h>
#include <hip/hip_cooperative_groups.h>
#include <math.h>

namespace cg = cooperative_groups;

#define NB 256     // batch
#define IC 1152    // input capsules
#define OC 10      // output capsules
#define OU 16      // output units
#define IK 8       // input units
#define KTOT (IC * IK)        // 9216
#define NTOT (OC * OU)        // 160
#define S_KS 16               // s-pass K-splits (576 k = 18 MFMA each)
#define BLP 584               // B-tile row pitch in shorts (576 + 8 pad)
#define GRID 512              // 2 blocks/CU guaranteed by launch_bounds(256,2)

typedef __attribute__((ext_vector_type(8))) short short8;
typedef __attribute__((ext_vector_type(4))) float f32x4;

static __device__ __forceinline__ unsigned short f2bf(float f) {
    unsigned u = __float_as_uint(f);
    unsigned r = (u + 0x7FFF + ((u >> 16) & 1)) >> 16;   // RNE
    return (unsigned short)r;
}

// ===================== fused cooperative kernel =====================
// prep -> [spass -> reduce+squash -> delta]x3 with grid.sync() at the 8
// former launch boundaries. GRID=512 + launch_bounds(256,2): the coop
// occupancy validation needs only 2 blocks/CU (VGPR+AGPR budget 256,
// LDS 18.7KB x2 = 37KB < 160KB) -- R1's 640@(256,3) was rejected because
// unified VGPR+AGPR exceeded the 170/wave needed for 3 blocks/CU.
__global__ __launch_bounds__(256, 2) void fused_kernel(
    const float* __restrict__ inp,        // [256][1152][8]
    const float* __restrict__ W,          // [1152][10][16][8]
    float* __restrict__ blog,             // [1152][10]
    float* __restrict__ part,             // [16][256][160]
    unsigned short* __restrict__ inpb,    // [256][9216] bf16
    unsigned short* __restrict__ inpT,    // [9216][256] bf16
    unsigned short* __restrict__ vT,      // [160][256]  bf16
    float* __restrict__ vout)             // [256][10][16]
{
    cg::grid_group grid = cg::this_grid();
    const int blk  = blockIdx.x;
    const int tid  = threadIdx.x;
    const int lane = tid & 63;
    const int wid  = tid >> 6;

    __shared__ unsigned short Bl[16 * BLP];   // 18.7 KB (reused as prep transpose buf)
    __shared__ float c_loc[72];

    // ---------------- prep: inp -> bf16 [256][9216] and transpose [9216][256]
    if (blk < 45) blog[blk * 256 + tid] = 0.f;
    for (int vb = blk; vb < 576; vb += GRID) {
        __syncthreads();                      // protect sh reuse across vb iters
        auto sh = (unsigned short (*)[65])Bl; // 64x65 shorts = 8.3 KB, fits in Bl
        const int kt = vb % 144;
        const int bt = vb / 144;
#pragma unroll
        for (int j = 0; j < 4; ++j) {
            int q     = j * 256 + tid;
            int b_loc = q >> 4;
            int kq    = (q & 15) * 4;
            float4 g = *(const float4*)&inp[(size_t)(bt * 64 + b_loc) * KTOT + kt * 64 + kq];
            unsigned short h0 = f2bf(g.x), h1 = f2bf(g.y), h2 = f2bf(g.z), h3 = f2bf(g.w);
            sh[kq][b_loc] = h0; sh[kq + 1][b_loc] = h1;
            sh[kq + 2][b_loc] = h2; sh[kq + 3][b_loc] = h3;
            short4 pk = { (short)h0, (short)h1, (short)h2, (short)h3 };
            *(short4*)&inpb[(size_t)(bt * 64 + b_loc) * KTOT + kt * 64 + kq] = pk;
        }
        __syncthreads();
#pragma unroll
        for (int j = 0; j < 4; ++j) {
            int q     = j * 256 + tid;
            int k_loc = q >> 4;
            int b4    = (q & 15) * 4;
            short4 pk = { (short)sh[k_loc][b4],     (short)sh[k_loc][b4 + 1],
                          (short)sh[k_loc][b4 + 2], (short)sh[k_loc][b4 + 3] };
            *(short4*)&inpT[(size_t)(kt * 64 + k_loc) * 256 + bt * 64 + b4] = pk;
        }
    }
    grid.sync();

    for (int t = 0; t < 3; ++t) {
        // ---------------- spass: 640 virtual blocks over 512 real ----------
        for (int vb = blk; vb < 640; vb += GRID) {
            __syncthreads();                  // protect Bl/c_loc reuse across vb
            const int nt   = vb % 10;         // output capsule o
            const int ks   = (vb / 10) % 16;  // k-split
            const int mtg  = vb / 160;        // 0..3
            const int l15  = lane & 15;
            const int koff = (lane >> 4) * 8;
            const int k0   = ks * 576;
            const int i0   = ks * 72;
            const int mt   = mtg * 4 + wid;

            if (tid < 72) {
                const float* br = &blog[(size_t)(i0 + tid) * OC];
                float x[OC], m = -1e30f;
#pragma unroll
                for (int o = 0; o < OC; ++o) { x[o] = br[o]; m = fmaxf(m, x[o]); }
                float ssum = 0.f;
#pragma unroll
                for (int o = 0; o < OC; ++o) ssum += expf(x[o] - m);
                c_loc[tid] = expf(x[nt] - m) / ssum;
            }
            __syncthreads();

#pragma unroll
            for (int jj = 0; jj < 5; ++jj) {
                int q = jj * 256 + tid;       // (i_loc, u) pairs: 72*16 = 1152
                if (q < 1152) {
                    int i_loc = q >> 4, u = q & 15;
                    const float* wr = W + (((size_t)(i0 + i_loc) * OC + nt) * OU + u) * IK;
                    float4 a = *(const float4*)wr;
                    float4 b = *(const float4*)(wr + 4);
                    float cc = c_loc[i_loc];
                    union { short8 v; unsigned short us[8]; } pk;
                    pk.us[0] = f2bf(cc * a.x); pk.us[1] = f2bf(cc * a.y);
                    pk.us[2] = f2bf(cc * a.z); pk.us[3] = f2bf(cc * a.w);
                    pk.us[4] = f2bf(cc * b.x); pk.us[5] = f2bf(cc * b.y);
                    pk.us[6] = f2bf(cc * b.z); pk.us[7] = f2bf(cc * b.w);
                    *(short8*)&Bl[u * BLP + i_loc * 8] = pk.v;
                }
            }
            __syncthreads();

            const unsigned short* ap  = inpb + (size_t)(mt * 16 + l15) * KTOT + k0 + koff;
            const unsigned short* bls = &Bl[l15 * BLP + koff];

            f32x4 acc = {0.f, 0.f, 0.f, 0.f};
#pragma unroll
            for (int kk = 0; kk < 18; ++kk) {
                short8 av = *(const short8*)(ap + kk * 32);
                short8 bv = *(const short8*)(bls + kk * 32);
                acc = __builtin_amdgcn_mfma_f32_16x16x32_bf16(av, bv, acc, 0, 0, 0);
            }

            float* pp = part + ((size_t)ks * NB + mt * 16 + (lane >> 4) * 4) * NTOT + nt * 16 + l15;
#pragma unroll
            for (int r = 0; r < 4; ++r)
                pp[(size_t)r * NTOT] = acc[r];
        }
        grid.sync();

        // ---------------- reduce partials + squash: 1 thread per element ---
        {
            int gtid = blk * 256 + tid;       // only blk < 160 active
            if (gtid < NB * NTOT) {
                float s = 0.f;
#pragma unroll
                for (int ksr = 0; ksr < 16; ++ksr)
                    s += part[(size_t)ksr * (NB * NTOT) + gtid];
                float sq = s * s;
                sq += __shfl_xor(sq, 1);      // sum over u (aligned 16-lane groups)
                sq += __shfl_xor(sq, 2);
                sq += __shfl_xor(sq, 4);
                sq += __shfl_xor(sq, 8);
                float vv = s * (sq / ((1.f + sq) * sqrtf(sq + 1e-9f)));
                if (t == 2) {
                    vout[gtid] = vv;          // only final v is observable
                } else {
                    int n = gtid % NTOT, b = gtid / NTOT;
                    vT[(size_t)n * 256 + b] = f2bf(vv);
                }
            }
        }

        if (t < 2) {
            grid.sync();
            // ---------------- delta: 2880 virtual waves over 2048 real -----
            for (int g = blk * 4 + wid; g < 2880; g += GRID * 4) {
                const int mt   = g % 576;
                const int ntp  = g / 576;     // 0..4 -> nt = ntp*2, ntp*2+1
                const int l15  = lane & 15;
                const int quad = lane >> 4;
                const int koff = quad * 8;
                const int nt0  = ntp * 2;

                const unsigned short* ap  = inpT + (size_t)(mt * 16 + l15) * 256 + koff;
                const unsigned short* bp0 = vT   + (size_t)(nt0 * 16 + l15) * 256 + koff;
                const unsigned short* bp1 = bp0 + 16 * 256;

                f32x4 acc0 = {0.f, 0.f, 0.f, 0.f};
                f32x4 acc1 = {0.f, 0.f, 0.f, 0.f};
#pragma unroll
                for (int kk = 0; kk < 8; ++kk) {
                    short8 av = *(const short8*)(ap  + kk * 32);
                    short8 b0 = *(const short8*)(bp0 + kk * 32);
                    short8 b1 = *(const short8*)(bp1 + kk * 32);
                    acc0 = __builtin_amdgcn_mfma_f32_16x16x32_bf16(av, b0, acc0, 0, 0, 0);
                    acc1 = __builtin_amdgcn_mfma_f32_16x16x32_bf16(av, b1, acc1, 0, 0, 0);
                }

                // lane holds G[m=quad*4+r][n=l15]; m -> i_loc = quad>>1, k=(quad&1)*4+r
                const int i = mt * 2 + (quad >> 1);
                const float* wr0 = W + (((size_t)i * OC + nt0) * OU + l15) * IK + (quad & 1) * 4;
                float4 wf0 = *(const float4*)wr0;
                float4 wf1 = *(const float4*)(wr0 + OU * IK);   // nt0+1 adjacent in W
                float w0 = wf0.x * acc0[0] + wf0.y * acc0[1] + wf0.z * acc0[2] + wf0.w * acc0[3];
                float w1 = wf1.x * acc1[0] + wf1.y * acc1[1] + wf1.z * acc1[2] + wf1.w * acc1[3];

#pragma unroll
                for (int d = 0; d < 5; ++d) {
                    int m = (d == 0) ? 16 : (1 << (d - 1));   // 16, 1, 2, 4, 8
                    w0 += __shfl_xor(w0, m);
                    w1 += __shfl_xor(w1, m);
                }

                if ((lane & 31) == 0) {       // one writer per (i,o), no atomics
                    blog[(size_t)i * OC + nt0]     += w0 * (1.0f / NB);
                    blog[(size_t)i * OC + nt0 + 1] += w1 * (1.0f / NB);
                }
            }
            grid.sync();
        }
    }
}

// ===================== fallback: proven multi-kernel path (127.9us) =====

__global__ __launch_bounds__(256) void prep_kernel(
    const float* __restrict__ inp,
    float* __restrict__ blog,
    unsigned short* __restrict__ inpb,
    unsigned short* __restrict__ inpT)
{
    const int kt  = blockIdx.x;
    const int bt  = blockIdx.y;
    const int tid = threadIdx.x;
    {
        int bid = blockIdx.y * 144 + blockIdx.x;
        if (bid < 45) blog[bid * 256 + tid] = 0.f;
    }
    __shared__ unsigned short sh[64][65];
#pragma unroll
    for (int j = 0; j < 4; ++j) {
        int q = j * 256 + tid;
        int b_loc = q >> 4;
        int kq = (q & 15) * 4;
        float4 g = *(const float4*)&inp[(size_t)(bt * 64 + b_loc) * KTOT + kt * 64 + kq];
        unsigned short h0 = f2bf(g.x), h1 = f2bf(g.y), h2 = f2bf(g.z), h3 = f2bf(g.w);
        sh[kq][b_loc] = h0; sh[kq + 1][b_loc] = h1;
        sh[kq + 2][b_loc] = h2; sh[kq + 3][b_loc] = h3;
        short4 pk = { (short)h0, (short)h1, (short)h2, (short)h3 };
        *(short4*)&inpb[(size_t)(bt * 64 + b_loc) * KTOT + kt * 64 + kq] = pk;
    }
    __syncthreads();
#pragma unroll
    for (int j = 0; j < 4; ++j) {
        int q = j * 256 + tid;
        int k_loc = q >> 4;
        int b4 = (q & 15) * 4;
        short4 pk = { (short)sh[k_loc][b4],     (short)sh[k_loc][b4 + 1],
                      (short)sh[k_loc][b4 + 2], (short)sh[k_loc][b4 + 3] };
        *(short4*)&inpT[(size_t)(kt * 64 + k_loc) * 256 + bt * 64 + b4] = pk;
    }
}

__global__ __launch_bounds__(256) void spass_kernel(
    const unsigned short* __restrict__ inpb,
    const float* __restrict__ W,
    const float* __restrict__ blog,
    float* __restrict__ part)
{
    const int bid  = blockIdx.x;
    const int nt   = bid % 10;
    const int ks   = (bid / 10) % 16;
    const int mtg  = bid / 160;
    const int tid  = threadIdx.x;
    const int w    = tid >> 6;
    const int lane = tid & 63;
    const int l15  = lane & 15;
    const int koff = (lane >> 4) * 8;
    const int k0   = ks * 576;
    const int i0   = ks * 72;
    const int mt   = mtg * 4 + w;

    __shared__ unsigned short Bl[16 * BLP];
    __shared__ float c_loc[72];

    if (tid < 72) {
        const float* br = &blog[(size_t)(i0 + tid) * OC];
        float x[OC], m = -1e30f;
#pragma unroll
        for (int o = 0; o < OC; ++o) { x[o] = br[o]; m = fmaxf(m, x[o]); }
        float ssum = 0.f;
#pragma unroll
        for (int o = 0; o < OC; ++o) ssum += expf(x[o] - m);
        c_loc[tid] = expf(x[nt] - m) / ssum;
    }
    __syncthreads();
#pragma unroll
    for (int jj = 0; jj < 5; ++jj) {
        int q = jj * 256 + tid;
        if (q < 1152) {
            int i_loc = q >> 4, u = q & 15;
            const float* wr = W + (((size_t)(i0 + i_loc) * OC + nt) * OU + u) * IK;
            float4 a = *(const float4*)wr;
            float4 b = *(const float4*)(wr + 4);
            float cc = c_loc[i_loc];
            union { short8 v; unsigned short us[8]; } pk;
            pk.us[0] = f2bf(cc * a.x); pk.us[1] = f2bf(cc * a.y);
            pk.us[2] = f2bf(cc * a.z); pk.us[3] = f2bf(cc * a.w);
            pk.us[4] = f2bf(cc * b.x); pk.us[5] = f2bf(cc * b.y);
            pk.us[6] = f2bf(cc * b.z); pk.us[7] = f2bf(cc * b.w);
            *(short8*)&Bl[u * BLP + i_loc * 8] = pk.v;
        }
    }
    __syncthreads();

    const unsigned short* ap  = inpb + (size_t)(mt * 16 + l15) * KTOT + k0 + koff;
    const unsigned short* bls = &Bl[l15 * BLP + koff];
    f32x4 acc = {0.f, 0.f, 0.f, 0.f};
#pragma unroll
    for (int kk = 0; kk < 18; ++kk) {
        short8 av = *(const short8*)(ap + kk * 32);
        short8 bv = *(const short8*)(bls + kk * 32);
        acc = __builtin_amdgcn_mfma_f32_16x16x32_bf16(av, bv, acc, 0, 0, 0);
    }
    float* pp = part + ((size_t)ks * NB + mt * 16 + (lane >> 4) * 4) * NTOT + nt * 16 + l15;
#pragma unroll
    for (int r = 0; r < 4; ++r)
        pp[(size_t)r * NTOT] = acc[r];
}

__global__ __launch_bounds__(256) void reduce_squash_kernel(
    const float* __restrict__ part, float* __restrict__ vout,
    unsigned short* __restrict__ vT)
{
    const int tid = threadIdx.x;
    const int el  = tid & 31;
    const int kl  = tid >> 5;
    const int e   = blockIdx.x * 32 + el;

    float a = part[(size_t)(kl * 2) * (NB * NTOT) + e]
            + part[(size_t)(kl * 2 + 1) * (NB * NTOT) + e];

    __shared__ float red[8][36];
    red[kl][el] = a;
    __syncthreads();

    if (tid < 32) {
        float s = ((red[0][el] + red[1][el]) + (red[2][el] + red[3][el]))
                + ((red[4][el] + red[5][el]) + (red[6][el] + red[7][el]));
        float sq = s * s;
        sq += __shfl_xor(sq, 1);
        sq += __shfl_xor(sq, 2);
        sq += __shfl_xor(sq, 4);
        sq += __shfl_xor(sq, 8);
        float vv = s * (sq / ((1.f + sq) * sqrtf(sq + 1e-9f)));
        vout[e] = vv;
        int n = e % NTOT, b = e / NTOT;
        vT[(size_t)n * 256 + b] = f2bf(vv);
    }
}

__global__ __launch_bounds__(256) void delta_kernel(
    const unsigned short* __restrict__ inpT,
    const unsigned short* __restrict__ vT,
    const float* __restrict__ W,
    float* __restrict__ blog)
{
    const int g    = blockIdx.x * 4 + (threadIdx.x >> 6);
    const int lane = threadIdx.x & 63;
    const int mt   = g % 576;
    const int ntp  = g / 576;
    const int l15  = lane & 15;
    const int quad = lane >> 4;
    const int koff = quad * 8;
    const int nt0  = ntp * 2;

    const unsigned short* ap  = inpT + (size_t)(mt * 16 + l15) * 256 + koff;
    const unsigned short* bp0 = vT   + (size_t)(nt0 * 16 + l15) * 256 + koff;
    const unsigned short* bp1 = bp0 + 16 * 256;

    f32x4 acc0 = {0.f, 0.f, 0.f, 0.f};
    f32x4 acc1 = {0.f, 0.f, 0.f, 0.f};
#pragma unroll
    for (int kk = 0; kk < 8; ++kk) {
        short8 av = *(const short8*)(ap  + kk * 32);
        short8 b0 = *(const short8*)(bp0 + kk * 32);
        short8 b1 = *(const short8*)(bp1 + kk * 32);
        acc0 = __builtin_amdgcn_mfma_f32_16x16x32_bf16(av, b0, acc0, 0, 0, 0);
        acc1 = __builtin_amdgcn_mfma_f32_16x16x32_bf16(av, b1, acc1, 0, 0, 0);
    }
    const int i = mt * 2 + (quad >> 1);
    const float* wr0 = W + (((size_t)i * OC + nt0) * OU + l15) * IK + (quad & 1) * 4;
    float4 wf0 = *(const float4*)wr0;
    float4 wf1 = *(const float4*)(wr0 + OU * IK);
    float w0 = wf0.x * acc0[0] + wf0.y * acc0[1] + wf0.z * acc0[2] + wf0.w * acc0[3];
    float w1 = wf1.x * acc1[0] + wf1.y * acc1[1] + wf1.z * acc1[2] + wf1.w * acc1[3];
#pragma unroll
    for (int d = 0; d < 5; ++d) {
        int m = (d == 0) ? 16 : (1 << (d - 1));
        w0 += __shfl_xor(w0, m);
        w1 += __shfl_xor(w1, m);
    }
    if ((lane & 31) == 0) {
        blog[(size_t)i * OC + nt0]     += w0 * (1.0f / NB);
        blog[(size_t)i * OC + nt0 + 1] += w1 * (1.0f / NB);
    }
}

extern "C" void kernel_launch(void* const* d_in, const int* in_sizes, int n_in,
                              void* d_out, int out_size, void* d_ws, size_t ws_size,
                              hipStream_t stream) {
    const float* inp = (const float*)d_in[0];   // [256][1152][8]
    const float* W   = (const float*)d_in[1];   // [1152][10][16][8]
    float* vout = (float*)d_out;                // [256][10][16]

    float* blog = (float*)d_ws;                              // 11,520 f
    float* part = blog + IC * OC;                            // 655,360 f
    unsigned short* inpb = (unsigned short*)(part + (size_t)S_KS * NB * NTOT);
    unsigned short* inpT = inpb + (size_t)NB * KTOT;         // 2,359,296 u16
    unsigned short* vT   = inpT + (size_t)KTOT * 256;        // 40,960 u16

    void* args[] = { (void*)&inp, (void*)&W, (void*)&blog, (void*)&part,
                     (void*)&inpb, (void*)&inpT, (void*)&vT, (void*)&vout };
    hipError_t err = hipLaunchCooperativeKernel(fused_kernel, dim3(GRID), dim3(256),
                                                args, 0u, stream);
    if (err != hipSuccess) {
        // graceful fallback: the verified multi-kernel path
        prep_kernel<<<dim3(144, 4), dim3(256), 0, stream>>>(inp, blog, inpb, inpT);
        for (int t = 0; t < 3; ++t) {
            spass_kernel<<<dim3(640), dim3(256), 0, stream>>>(inpb, W, blog, part);
            reduce_squash_kernel<<<dim3(NB * NTOT / 32), dim3(256), 0, stream>>>(part, vout, vT);
            if (t < 2)
                delta_kernel<<<dim3(720), dim3(256), 0, stream>>>(inpT, vT, W, blog);
        }
    }
}

// Round 3
// 448.802 us; speedup vs baseline: 1.3539x; 1.3539x over previous
//
#include <hip/hip_runtime.h>
#include <math.h>

#define NB 256     // batch
#define IC 1152    // input capsules
#define OC 10      // output capsules
#define OU 16      // output units
#define IK 8       // input units
#define KTOT (IC * IK)        // 9216
#define NTOT (OC * OU)        // 160
#define S_KS 16               // s-pass K-splits (576 k = 18 MFMA each)
#define BLP 584               // B-tile row pitch in shorts (576 + 8 pad)
#define GRID 512              // 2 blocks/CU guaranteed by launch_bounds(256,2)

typedef __attribute__((ext_vector_type(8))) short short8;
typedef __attribute__((ext_vector_type(4))) float f32x4;

static __device__ __forceinline__ unsigned short f2bf(float f) {
    unsigned u = __float_as_uint(f);
    unsigned r = (u + 0x7FFF + ((u >> 16) & 1)) >> 16;   // RNE
    return (unsigned short)r;
}

// Fast grid barrier. R2 evidence: cg::grid_group::sync() costs ~68us each
// (548us kernel, 99% idle, 8 syncs). This one: release-arrive (atomicAdd
// agent-scope emits waitcnt+buffer_wbl2 sc1 -> cross-XCD visibility per
// G16), relaxed sc1 polling (no per-poll cache inv), one acquire fence on
// exit (buffer_inv sc1). Monotone target ph*GRID -> no reset race; host
// memsets the counter to 0 before each launch.
static __device__ __forceinline__ void gbar(unsigned* bar, unsigned ph) {
    __syncthreads();   // drains all waves' stores to L2 (vmcnt0 before s_barrier)
    if (threadIdx.x == 0) {
        __hip_atomic_fetch_add(bar, 1u, __ATOMIC_RELEASE, __HIP_MEMORY_SCOPE_AGENT);
        while (__hip_atomic_load(bar, __ATOMIC_RELAXED, __HIP_MEMORY_SCOPE_AGENT) < ph * GRID)
            __builtin_amdgcn_s_sleep(1);
        __builtin_amdgcn_fence(__ATOMIC_ACQUIRE, "agent");
    }
    __syncthreads();
}

// ===================== fused cooperative kernel =====================
// prep -> [spass -> reduce+squash -> delta]x3, 8 custom grid barriers.
// Cooperative launch kept ONLY for the co-residency guarantee (GRID=512
// @ launch_bounds(256,2) passed validation in R2).
__global__ __launch_bounds__(256, 2) void fused_kernel(
    const float* __restrict__ inp,        // [256][1152][8]
    const float* __restrict__ W,          // [1152][10][16][8]
    float* __restrict__ blog,             // [1152][10]
    float* __restrict__ part,             // [16][256][160]
    unsigned short* __restrict__ inpb,    // [256][9216] bf16
    unsigned short* __restrict__ inpT,    // [9216][256] bf16
    unsigned short* __restrict__ vT,      // [160][256]  bf16
    float* __restrict__ vout,             // [256][10][16]
    unsigned* __restrict__ bar)           // grid-barrier counter (memset 0)
{
    const int blk  = blockIdx.x;
    const int tid  = threadIdx.x;
    const int lane = tid & 63;
    const int wid  = tid >> 6;
    unsigned ph = 0;

    __shared__ unsigned short Bl[16 * BLP];   // 18.7 KB (reused as prep transpose buf)
    __shared__ float c_loc[72];

    // ---------------- prep: inp -> bf16 [256][9216] and transpose [9216][256]
    if (blk < 45) blog[blk * 256 + tid] = 0.f;
    for (int vb = blk; vb < 576; vb += GRID) {
        __syncthreads();                      // protect sh reuse across vb iters
        auto sh = (unsigned short (*)[65])Bl; // 64x65 shorts = 8.3 KB, fits in Bl
        const int kt = vb % 144;
        const int bt = vb / 144;
#pragma unroll
        for (int j = 0; j < 4; ++j) {
            int q     = j * 256 + tid;
            int b_loc = q >> 4;
            int kq    = (q & 15) * 4;
            float4 g = *(const float4*)&inp[(size_t)(bt * 64 + b_loc) * KTOT + kt * 64 + kq];
            unsigned short h0 = f2bf(g.x), h1 = f2bf(g.y), h2 = f2bf(g.z), h3 = f2bf(g.w);
            sh[kq][b_loc] = h0; sh[kq + 1][b_loc] = h1;
            sh[kq + 2][b_loc] = h2; sh[kq + 3][b_loc] = h3;
            short4 pk = { (short)h0, (short)h1, (short)h2, (short)h3 };
            *(short4*)&inpb[(size_t)(bt * 64 + b_loc) * KTOT + kt * 64 + kq] = pk;
        }
        __syncthreads();
#pragma unroll
        for (int j = 0; j < 4; ++j) {
            int q     = j * 256 + tid;
            int k_loc = q >> 4;
            int b4    = (q & 15) * 4;
            short4 pk = { (short)sh[k_loc][b4],     (short)sh[k_loc][b4 + 1],
                          (short)sh[k_loc][b4 + 2], (short)sh[k_loc][b4 + 3] };
            *(short4*)&inpT[(size_t)(kt * 64 + k_loc) * 256 + bt * 64 + b4] = pk;
        }
    }
    gbar(bar, ++ph);

    for (int t = 0; t < 3; ++t) {
        // ---------------- spass: 640 virtual blocks over 512 real ----------
        for (int vb = blk; vb < 640; vb += GRID) {
            __syncthreads();                  // protect Bl/c_loc reuse across vb
            const int nt   = vb % 10;         // output capsule o
            const int ks   = (vb / 10) % 16;  // k-split
            const int mtg  = vb / 160;        // 0..3
            const int l15  = lane & 15;
            const int koff = (lane >> 4) * 8;
            const int k0   = ks * 576;
            const int i0   = ks * 72;
            const int mt   = mtg * 4 + wid;

            if (tid < 72) {
                const float* br = &blog[(size_t)(i0 + tid) * OC];
                float x[OC], m = -1e30f;
#pragma unroll
                for (int o = 0; o < OC; ++o) { x[o] = br[o]; m = fmaxf(m, x[o]); }
                float ssum = 0.f;
#pragma unroll
                for (int o = 0; o < OC; ++o) ssum += expf(x[o] - m);
                c_loc[tid] = expf(x[nt] - m) / ssum;
            }
            __syncthreads();

#pragma unroll
            for (int jj = 0; jj < 5; ++jj) {
                int q = jj * 256 + tid;       // (i_loc, u) pairs: 72*16 = 1152
                if (q < 1152) {
                    int i_loc = q >> 4, u = q & 15;
                    const float* wr = W + (((size_t)(i0 + i_loc) * OC + nt) * OU + u) * IK;
                    float4 a = *(const float4*)wr;
                    float4 b = *(const float4*)(wr + 4);
                    float cc = c_loc[i_loc];
                    union { short8 v; unsigned short us[8]; } pk;
                    pk.us[0] = f2bf(cc * a.x); pk.us[1] = f2bf(cc * a.y);
                    pk.us[2] = f2bf(cc * a.z); pk.us[3] = f2bf(cc * a.w);
                    pk.us[4] = f2bf(cc * b.x); pk.us[5] = f2bf(cc * b.y);
                    pk.us[6] = f2bf(cc * b.z); pk.us[7] = f2bf(cc * b.w);
                    *(short8*)&Bl[u * BLP + i_loc * 8] = pk.v;
                }
            }
            __syncthreads();

            const unsigned short* ap  = inpb + (size_t)(mt * 16 + l15) * KTOT + k0 + koff;
            const unsigned short* bls = &Bl[l15 * BLP + koff];

            f32x4 acc = {0.f, 0.f, 0.f, 0.f};
#pragma unroll
            for (int kk = 0; kk < 18; ++kk) {
                short8 av = *(const short8*)(ap + kk * 32);
                short8 bv = *(const short8*)(bls + kk * 32);
                acc = __builtin_amdgcn_mfma_f32_16x16x32_bf16(av, bv, acc, 0, 0, 0);
            }

            float* pp = part + ((size_t)ks * NB + mt * 16 + (lane >> 4) * 4) * NTOT + nt * 16 + l15;
#pragma unroll
            for (int r = 0; r < 4; ++r)
                pp[(size_t)r * NTOT] = acc[r];
        }
        gbar(bar, ++ph);

        // ---------------- reduce partials + squash: 1 thread per element ---
        {
            int gtid = blk * 256 + tid;       // only blk < 160 active
            if (gtid < NB * NTOT) {
                float s = 0.f;
#pragma unroll
                for (int ksr = 0; ksr < 16; ++ksr)
                    s += part[(size_t)ksr * (NB * NTOT) + gtid];
                float sq = s * s;
                sq += __shfl_xor(sq, 1);      // sum over u (aligned 16-lane groups)
                sq += __shfl_xor(sq, 2);
                sq += __shfl_xor(sq, 4);
                sq += __shfl_xor(sq, 8);
                float vv = s * (sq / ((1.f + sq) * sqrtf(sq + 1e-9f)));
                if (t == 2) {
                    vout[gtid] = vv;          // only final v is observable
                } else {
                    int n = gtid % NTOT, b = gtid / NTOT;
                    vT[(size_t)n * 256 + b] = f2bf(vv);
                }
            }
        }

        if (t < 2) {
            gbar(bar, ++ph);
            // ---------------- delta: 2880 virtual waves over 2048 real -----
            for (int g = blk * 4 + wid; g < 2880; g += GRID * 4) {
                const int mt   = g % 576;
                const int ntp  = g / 576;     // 0..4 -> nt = ntp*2, ntp*2+1
                const int l15  = lane & 15;
                const int quad = lane >> 4;
                const int koff = quad * 8;
                const int nt0  = ntp * 2;

                const unsigned short* ap  = inpT + (size_t)(mt * 16 + l15) * 256 + koff;
                const unsigned short* bp0 = vT   + (size_t)(nt0 * 16 + l15) * 256 + koff;
                const unsigned short* bp1 = bp0 + 16 * 256;

                f32x4 acc0 = {0.f, 0.f, 0.f, 0.f};
                f32x4 acc1 = {0.f, 0.f, 0.f, 0.f};
#pragma unroll
                for (int kk = 0; kk < 8; ++kk) {
                    short8 av = *(const short8*)(ap  + kk * 32);
                    short8 b0 = *(const short8*)(bp0 + kk * 32);
                    short8 b1 = *(const short8*)(bp1 + kk * 32);
                    acc0 = __builtin_amdgcn_mfma_f32_16x16x32_bf16(av, b0, acc0, 0, 0, 0);
                    acc1 = __builtin_amdgcn_mfma_f32_16x16x32_bf16(av, b1, acc1, 0, 0, 0);
                }

                // lane holds G[m=quad*4+r][n=l15]; m -> i_loc = quad>>1, k=(quad&1)*4+r
                const int i = mt * 2 + (quad >> 1);
                const float* wr0 = W + (((size_t)i * OC + nt0) * OU + l15) * IK + (quad & 1) * 4;
                float4 wf0 = *(const float4*)wr0;
                float4 wf1 = *(const float4*)(wr0 + OU * IK);   // nt0+1 adjacent in W
                float w0 = wf0.x * acc0[0] + wf0.y * acc0[1] + wf0.z * acc0[2] + wf0.w * acc0[3];
                float w1 = wf1.x * acc1[0] + wf1.y * acc1[1] + wf1.z * acc1[2] + wf1.w * acc1[3];

#pragma unroll
                for (int d = 0; d < 5; ++d) {
                    int m = (d == 0) ? 16 : (1 << (d - 1));   // 16, 1, 2, 4, 8
                    w0 += __shfl_xor(w0, m);
                    w1 += __shfl_xor(w1, m);
                }

                if ((lane & 31) == 0) {       // one writer per (i,o), no atomics
                    blog[(size_t)i * OC + nt0]     += w0 * (1.0f / NB);
                    blog[(size_t)i * OC + nt0 + 1] += w1 * (1.0f / NB);
                }
            }
            gbar(bar, ++ph);
        }
    }
}

// ===================== fallback: proven multi-kernel path (127.9us) =====

__global__ __launch_bounds__(256) void prep_kernel(
    const float* __restrict__ inp,
    float* __restrict__ blog,
    unsigned short* __restrict__ inpb,
    unsigned short* __restrict__ inpT)
{
    const int kt  = blockIdx.x;
    const int bt  = blockIdx.y;
    const int tid = threadIdx.x;
    {
        int bid = blockIdx.y * 144 + blockIdx.x;
        if (bid < 45) blog[bid * 256 + tid] = 0.f;
    }
    __shared__ unsigned short sh[64][65];
#pragma unroll
    for (int j = 0; j < 4; ++j) {
        int q = j * 256 + tid;
        int b_loc = q >> 4;
        int kq = (q & 15) * 4;
        float4 g = *(const float4*)&inp[(size_t)(bt * 64 + b_loc) * KTOT + kt * 64 + kq];
        unsigned short h0 = f2bf(g.x), h1 = f2bf(g.y), h2 = f2bf(g.z), h3 = f2bf(g.w);
        sh[kq][b_loc] = h0; sh[kq + 1][b_loc] = h1;
        sh[kq + 2][b_loc] = h2; sh[kq + 3][b_loc] = h3;
        short4 pk = { (short)h0, (short)h1, (short)h2, (short)h3 };
        *(short4*)&inpb[(size_t)(bt * 64 + b_loc) * KTOT + kt * 64 + kq] = pk;
    }
    __syncthreads();
#pragma unroll
    for (int j = 0; j < 4; ++j) {
        int q = j * 256 + tid;
        int k_loc = q >> 4;
        int b4 = (q & 15) * 4;
        short4 pk = { (short)sh[k_loc][b4],     (short)sh[k_loc][b4 + 1],
                      (short)sh[k_loc][b4 + 2], (short)sh[k_loc][b4 + 3] };
        *(short4*)&inpT[(size_t)(kt * 64 + k_loc) * 256 + bt * 64 + b4] = pk;
    }
}

__global__ __launch_bounds__(256) void spass_kernel(
    const unsigned short* __restrict__ inpb,
    const float* __restrict__ W,
    const float* __restrict__ blog,
    float* __restrict__ part)
{
    const int bid  = blockIdx.x;
    const int nt   = bid % 10;
    const int ks   = (bid / 10) % 16;
    const int mtg  = bid / 160;
    const int tid  = threadIdx.x;
    const int w    = tid >> 6;
    const int lane = tid & 63;
    const int l15  = lane & 15;
    const int koff = (lane >> 4) * 8;
    const int k0   = ks * 576;
    const int i0   = ks * 72;
    const int mt   = mtg * 4 + w;

    __shared__ unsigned short Bl[16 * BLP];
    __shared__ float c_loc[72];

    if (tid < 72) {
        const float* br = &blog[(size_t)(i0 + tid) * OC];
        float x[OC], m = -1e30f;
#pragma unroll
        for (int o = 0; o < OC; ++o) { x[o] = br[o]; m = fmaxf(m, x[o]); }
        float ssum = 0.f;
#pragma unroll
        for (int o = 0; o < OC; ++o) ssum += expf(x[o] - m);
        c_loc[tid] = expf(x[nt] - m) / ssum;
    }
    __syncthreads();
#pragma unroll
    for (int jj = 0; jj < 5; ++jj) {
        int q = jj * 256 + tid;
        if (q < 1152) {
            int i_loc = q >> 4, u = q & 15;
            const float* wr = W + (((size_t)(i0 + i_loc) * OC + nt) * OU + u) * IK;
            float4 a = *(const float4*)wr;
            float4 b = *(const float4*)(wr + 4);
            float cc = c_loc[i_loc];
            union { short8 v; unsigned short us[8]; } pk;
            pk.us[0] = f2bf(cc * a.x); pk.us[1] = f2bf(cc * a.y);
            pk.us[2] = f2bf(cc * a.z); pk.us[3] = f2bf(cc * a.w);
            pk.us[4] = f2bf(cc * b.x); pk.us[5] = f2bf(cc * b.y);
            pk.us[6] = f2bf(cc * b.z); pk.us[7] = f2bf(cc * b.w);
            *(short8*)&Bl[u * BLP + i_loc * 8] = pk.v;
        }
    }
    __syncthreads();

    const unsigned short* ap  = inpb + (size_t)(mt * 16 + l15) * KTOT + k0 + koff;
    const unsigned short* bls = &Bl[l15 * BLP + koff];
    f32x4 acc = {0.f, 0.f, 0.f, 0.f};
#pragma unroll
    for (int kk = 0; kk < 18; ++kk) {
        short8 av = *(const short8*)(ap + kk * 32);
        short8 bv = *(const short8*)(bls + kk * 32);
        acc = __builtin_amdgcn_mfma_f32_16x16x32_bf16(av, bv, acc, 0, 0, 0);
    }
    float* pp = part + ((size_t)ks * NB + mt * 16 + (lane >> 4) * 4) * NTOT + nt * 16 + l15;
#pragma unroll
    for (int r = 0; r < 4; ++r)
        pp[(size_t)r * NTOT] = acc[r];
}

__global__ __launch_bounds__(256) void reduce_squash_kernel(
    const float* __restrict__ part, float* __restrict__ vout,
    unsigned short* __restrict__ vT)
{
    const int tid = threadIdx.x;
    const int el  = tid & 31;
    const int kl  = tid >> 5;
    const int e   = blockIdx.x * 32 + el;

    float a = part[(size_t)(kl * 2) * (NB * NTOT) + e]
            + part[(size_t)(kl * 2 + 1) * (NB * NTOT) + e];

    __shared__ float red[8][36];
    red[kl][el] = a;
    __syncthreads();

    if (tid < 32) {
        float s = ((red[0][el] + red[1][el]) + (red[2][el] + red[3][el]))
                + ((red[4][el] + red[5][el]) + (red[6][el] + red[7][el]));
        float sq = s * s;
        sq += __shfl_xor(sq, 1);
        sq += __shfl_xor(sq, 2);
        sq += __shfl_xor(sq, 4);
        sq += __shfl_xor(sq, 8);
        float vv = s * (sq / ((1.f + sq) * sqrtf(sq + 1e-9f)));
        vout[e] = vv;
        int n = e % NTOT, b = e / NTOT;
        vT[(size_t)n * 256 + b] = f2bf(vv);
    }
}

__global__ __launch_bounds__(256) void delta_kernel(
    const unsigned short* __restrict__ inpT,
    const unsigned short* __restrict__ vT,
    const float* __restrict__ W,
    float* __restrict__ blog)
{
    const int g    = blockIdx.x * 4 + (threadIdx.x >> 6);
    const int lane = threadIdx.x & 63;
    const int mt   = g % 576;
    const int ntp  = g / 576;
    const int l15  = lane & 15;
    const int quad = lane >> 4;
    const int koff = quad * 8;
    const int nt0  = ntp * 2;

    const unsigned short* ap  = inpT + (size_t)(mt * 16 + l15) * 256 + koff;
    const unsigned short* bp0 = vT   + (size_t)(nt0 * 16 + l15) * 256 + koff;
    const unsigned short* bp1 = bp0 + 16 * 256;

    f32x4 acc0 = {0.f, 0.f, 0.f, 0.f};
    f32x4 acc1 = {0.f, 0.f, 0.f, 0.f};
#pragma unroll
    for (int kk = 0; kk < 8; ++kk) {
        short8 av = *(const short8*)(ap  + kk * 32);
        short8 b0 = *(const short8*)(bp0 + kk * 32);
        short8 b1 = *(const short8*)(bp1 + kk * 32);
        acc0 = __builtin_amdgcn_mfma_f32_16x16x32_bf16(av, b0, acc0, 0, 0, 0);
        acc1 = __builtin_amdgcn_mfma_f32_16x16x32_bf16(av, b1, acc1, 0, 0, 0);
    }
    const int i = mt * 2 + (quad >> 1);
    const float* wr0 = W + (((size_t)i * OC + nt0) * OU + l15) * IK + (quad & 1) * 4;
    float4 wf0 = *(const float4*)wr0;
    float4 wf1 = *(const float4*)(wr0 + OU * IK);
    float w0 = wf0.x * acc0[0] + wf0.y * acc0[1] + wf0.z * acc0[2] + wf0.w * acc0[3];
    float w1 = wf1.x * acc1[0] + wf1.y * acc1[1] + wf1.z * acc1[2] + wf1.w * acc1[3];
#pragma unroll
    for (int d = 0; d < 5; ++d) {
        int m = (d == 0) ? 16 : (1 << (d - 1));
        w0 += __shfl_xor(w0, m);
        w1 += __shfl_xor(w1, m);
    }
    if ((lane & 31) == 0) {
        blog[(size_t)i * OC + nt0]     += w0 * (1.0f / NB);
        blog[(size_t)i * OC + nt0 + 1] += w1 * (1.0f / NB);
    }
}

extern "C" void kernel_launch(void* const* d_in, const int* in_sizes, int n_in,
                              void* d_out, int out_size, void* d_ws, size_t ws_size,
                              hipStream_t stream) {
    const float* inp = (const float*)d_in[0];   // [256][1152][8]
    const float* W   = (const float*)d_in[1];   // [1152][10][16][8]
    float* vout = (float*)d_out;                // [256][10][16]

    float* blog = (float*)d_ws;                              // 11,520 f
    float* part = blog + IC * OC;                            // 655,360 f
    unsigned short* inpb = (unsigned short*)(part + (size_t)S_KS * NB * NTOT);
    unsigned short* inpT = inpb + (size_t)NB * KTOT;         // 2,359,296 u16
    unsigned short* vT   = inpT + (size_t)KTOT * 256;        // 40,960 u16
    // barrier counter: next 128B-aligned spot after vT
    size_t bar_off = (((size_t)(vT + NTOT * 256) - (size_t)d_ws) + 127) & ~(size_t)127;
    unsigned* bar = (unsigned*)((char*)d_ws + bar_off);

    hipMemsetAsync(bar, 0, 64, stream);         // reset barrier state each replay

    void* args[] = { (void*)&inp, (void*)&W, (void*)&blog, (void*)&part,
                     (void*)&inpb, (void*)&inpT, (void*)&vT, (void*)&vout,
                     (void*)&bar };
    hipError_t err = hipLaunchCooperativeKernel(fused_kernel, dim3(GRID), dim3(256),
                                                args, 0u, stream);
    if (err != hipSuccess) {
        // graceful fallback: the verified multi-kernel path
        prep_kernel<<<dim3(144, 4), dim3(256), 0, stream>>>(inp, blog, inpb, inpT);
        for (int t = 0; t < 3; ++t) {
            spass_kernel<<<dim3(640), dim3(256), 0, stream>>>(inpb, W, blog, part);
            reduce_squash_kernel<<<dim3(NB * NTOT / 32), dim3(256), 0, stream>>>(part, vout, vT);
            if (t < 2)
                delta_kernel<<<dim3(720), dim3(256), 0, stream>>>(inpT, vT, W, blog);
        }
    }
}

// Round 4
// 226.918 us; speedup vs baseline: 2.6778x; 1.9778x over previous
//
#include <hip/hip_runtime.h>
#include <math.h>

#define NB 256     // batch
#define IC 1152    // input capsules
#define OC 10      // output capsules
#define OU 16      // output units
#define IK 8       // input units
#define KTOT (IC * IK)        // 9216
#define NTOT (OC * OU)        // 160
#define S_KS 16               // s-pass K-splits (576 k = 18 MFMA each)
#define BLP 584   // B-tile row pitch in shorts (576 + 8 pad)
#define GRID 512              // 2 blocks/CU guaranteed by launch_bounds(256,2)
#define SUBN 8                // barrier sub-groups (64 blocks each)

typedef __attribute__((ext_vector_type(8))) short short8;
typedef __attribute__((ext_vector_type(4))) float f32x4;
typedef unsigned int u32;
typedef unsigned long long u64;

static __device__ __forceinline__ unsigned short f2bf(float f) {
    unsigned u = __float_as_uint(f);
    unsigned r = (u + 0x7FFF + ((u >> 16) & 1)) >> 16;   // RNE
    return (unsigned short)r;
}

// --- device-coherent (sc1, coherent-point) accessors: store lands at L3 at
// store time; load bypasses L1/L2. Relaxed => NO buffer_wbl2/buffer_inv.
static __device__ __forceinline__ void st_u32(u32* p, u32 v) {
    __hip_atomic_store(p, v, __ATOMIC_RELAXED, __HIP_MEMORY_SCOPE_AGENT);
}
static __device__ __forceinline__ u32 ld_u32(const u32* p) {
    return __hip_atomic_load(p, __ATOMIC_RELAXED, __HIP_MEMORY_SCOPE_AGENT);
}
static __device__ __forceinline__ void st_u64(u64* p, u64 v) {
    __hip_atomic_store(p, v, __ATOMIC_RELAXED, __HIP_MEMORY_SCOPE_AGENT);
}
static __device__ __forceinline__ u64 ld_u64(const u64* p) {
    return __hip_atomic_load(p, __ATOMIC_RELAXED, __HIP_MEMORY_SCOPE_AGENT);
}
static __device__ __forceinline__ void stf(float* p, float v) { st_u32((u32*)p, __float_as_uint(v)); }
static __device__ __forceinline__ float ldf(const float* p)   { return __uint_as_float(ld_u32((const u32*)p)); }

// load 8 coherent f32 and convert to bf16x8 (== old bf16 vT path bit-exactly)
static __device__ __forceinline__ short8 ld_v8(const float* p) {
    short8 r;
#pragma unroll
    for (int j = 0; j < 4; ++j) {
        union { u64 q; float f[2]; } U;
        U.q = ld_u64((const u64*)(p + j * 2));
        r[j * 2]     = (short)f2bf(U.f[0]);
        r[j * 2 + 1] = (short)f2bf(U.f[1]);
    }
    return r;
}

// Counter-only two-level grid barrier. R3 post-mortem: per-block RELEASE
// (buffer_wbl2) + ACQUIRE (buffer_inv) + 512 same-line sc1 RMWs = ~36us per
// barrier. Coherence now lives in the sc1 data path, so the barrier needs
// only ordering: __syncthreads() drains vmcnt(0) per wave (data at L3
// before arrival RMW). subctr: 8 lines x 64 contenders; gctr: 8 arrivals;
// rel[sub]: <=64 pollers per line. All counters monotone; host memsets 0.
static __device__ __forceinline__ void gbar(u32* bar, unsigned ph) {
    __syncthreads();
    if (threadIdx.x == 0) {
        const int sub = blockIdx.x & (SUBN - 1);
        u32* subc = bar + sub * 32;
        u32* gctr = bar + SUBN * 32;
        u32* rel  = bar + SUBN * 32 + 32 + sub * 32;
        unsigned old = __hip_atomic_fetch_add(subc, 1u, __ATOMIC_RELAXED, __HIP_MEMORY_SCOPE_AGENT);
        if (old == ph * (GRID / SUBN) - 1u) {        // last arrival in sub-group
            __hip_atomic_fetch_add(gctr, 1u, __ATOMIC_RELAXED, __HIP_MEMORY_SCOPE_AGENT);
            while (__hip_atomic_load(gctr, __ATOMIC_RELAXED, __HIP_MEMORY_SCOPE_AGENT) < ph * SUBN)
                __builtin_amdgcn_s_sleep(2);
            __hip_atomic_store(rel, ph, __ATOMIC_RELAXED, __HIP_MEMORY_SCOPE_AGENT);
        } else {
            while (__hip_atomic_load(rel, __ATOMIC_RELAXED, __HIP_MEMORY_SCOPE_AGENT) < ph)
                __builtin_amdgcn_s_sleep(2);
        }
    }
    __syncthreads();
}

// ===================== fused cooperative kernel =====================
// prep -> [spass -> reduce+squash -> delta]x3, 8 counter-only barriers.
// Mutable intermediates (part, vTf, blog): sc1 store + sc1 load everywhere.
// Immutable bulk (inpb, inpT): sc1 store once in prep, plain cached reads.
__global__ __launch_bounds__(256, 2) void fused_kernel(
    const float* __restrict__ inp,        // [256][1152][8]
    const float* __restrict__ W,          // [1152][10][16][8]
    float* __restrict__ blog,             // [1152][10]          (sc1)
    float* __restrict__ part,             // [16][256][160]      (sc1)
    unsigned short* __restrict__ inpb,    // [256][9216] bf16    (immutable)
    unsigned short* __restrict__ inpT,    // [9216][256] bf16    (immutable)
    float* __restrict__ vTf,              // [160][256] f32      (sc1)
    float* __restrict__ vout,             // [256][10][16]
    u32* bar)                             // barrier counters (memset 0)
{
    const int blk  = blockIdx.x;
    const int tid  = threadIdx.x;
    const int lane = tid & 63;
    const int wid  = tid >> 6;
    unsigned ph = 0;

    __shared__ unsigned short Bl[16 * BLP];   // 18.7 KB (reused as prep transpose buf)
    __shared__ float c_loc[72];

    // ---------------- prep: inp -> bf16 [256][9216] and transpose [9216][256]
    if (blk < 45) stf(&blog[blk * 256 + tid], 0.f);
    for (int vb = blk; vb < 576; vb += GRID) {
        __syncthreads();                      // protect sh reuse across vb iters
        auto sh = (unsigned short (*)[65])Bl; // 64x65 shorts = 8.3 KB, fits in Bl
        const int kt = vb % 144;
        const int bt = vb / 144;
#pragma unroll
        for (int j = 0; j < 4; ++j) {
            int q     = j * 256 + tid;
            int b_loc = q >> 4;
            int kq    = (q & 15) * 4;
            float4 g = *(const float4*)&inp[(size_t)(bt * 64 + b_loc) * KTOT + kt * 64 + kq];
            unsigned short h0 = f2bf(g.x), h1 = f2bf(g.y), h2 = f2bf(g.z), h3 = f2bf(g.w);
            sh[kq][b_loc] = h0; sh[kq + 1][b_loc] = h1;
            sh[kq + 2][b_loc] = h2; sh[kq + 3][b_loc] = h3;
            u64 pk = (u64)h0 | ((u64)h1 << 16) | ((u64)h2 << 32) | ((u64)h3 << 48);
            st_u64((u64*)&inpb[(size_t)(bt * 64 + b_loc) * KTOT + kt * 64 + kq], pk);
        }
        __syncthreads();
#pragma unroll
        for (int j = 0; j < 4; ++j) {
            int q     = j * 256 + tid;
            int k_loc = q >> 4;
            int b4    = (q & 15) * 4;
            u64 pk = (u64)sh[k_loc][b4] | ((u64)sh[k_loc][b4 + 1] << 16)
                   | ((u64)sh[k_loc][b4 + 2] << 32) | ((u64)sh[k_loc][b4 + 3] << 48);
            st_u64((u64*)&inpT[(size_t)(kt * 64 + k_loc) * 256 + bt * 64 + b4], pk);
        }
    }
    gbar(bar, ++ph);

    for (int t = 0; t < 3; ++t) {
        // ---------------- spass: 640 virtual blocks over 512 real ----------
        for (int vb = blk; vb < 640; vb += GRID) {
            __syncthreads();                  // protect Bl/c_loc reuse across vb
            const int nt   = vb % 10;         // output capsule o
            const int ks   = (vb / 10) % 16;  // k-split
            const int mtg  = vb / 160;        // 0..3
            const int l15  = lane & 15;
            const int koff = (lane >> 4) * 8;
            const int k0   = ks * 576;
            const int i0   = ks * 72;
            const int mt   = mtg * 4 + wid;

            if (tid < 72) {
                const float* br = &blog[(size_t)(i0 + tid) * OC];
                float x[OC], m = -1e30f;
#pragma unroll
                for (int o = 0; o < OC; ++o) { x[o] = ldf(&br[o]); m = fmaxf(m, x[o]); }
                float ssum = 0.f;
#pragma unroll
                for (int o = 0; o < OC; ++o) ssum += expf(x[o] - m);
                c_loc[tid] = expf(x[nt] - m) / ssum;
            }
            __syncthreads();

#pragma unroll
            for (int jj = 0; jj < 5; ++jj) {
                int q = jj * 256 + tid;       // (i_loc, u) pairs: 72*16 = 1152
                if (q < 1152) {
                    int i_loc = q >> 4, u = q & 15;
                    const float* wr = W + (((size_t)(i0 + i_loc) * OC + nt) * OU + u) * IK;
                    float4 a = *(const float4*)wr;
                    float4 b = *(const float4*)(wr + 4);
                    float cc = c_loc[i_loc];
                    union { short8 v; unsigned short us[8]; } pk;
                    pk.us[0] = f2bf(cc * a.x); pk.us[1] = f2bf(cc * a.y);
                    pk.us[2] = f2bf(cc * a.z); pk.us[3] = f2bf(cc * a.w);
                    pk.us[4] = f2bf(cc * b.x); pk.us[5] = f2bf(cc * b.y);
                    pk.us[6] = f2bf(cc * b.z); pk.us[7] = f2bf(cc * b.w);
                    *(short8*)&Bl[u * BLP + i_loc * 8] = pk.v;
                }
            }
            __syncthreads();

            const unsigned short* ap  = inpb + (size_t)(mt * 16 + l15) * KTOT + k0 + koff;
            const unsigned short* bls = &Bl[l15 * BLP + koff];

            f32x4 acc = {0.f, 0.f, 0.f, 0.f};
#pragma unroll
            for (int kk = 0; kk < 18; ++kk) {
                short8 av = *(const short8*)(ap + kk * 32);   // plain: immutable
                short8 bv = *(const short8*)(bls + kk * 32);
                acc = __builtin_amdgcn_mfma_f32_16x16x32_bf16(av, bv, acc, 0, 0, 0);
            }

            float* pp = part + ((size_t)ks * NB + mt * 16 + (lane >> 4) * 4) * NTOT + nt * 16 + l15;
#pragma unroll
            for (int r = 0; r < 4; ++r)
                stf(&pp[(size_t)r * NTOT], acc[r]);
        }
        gbar(bar, ++ph);

        // ---------------- reduce partials + squash: 1 thread per element ---
        {
            int gtid = blk * 256 + tid;       // only blk < 160 active
            if (gtid < NB * NTOT) {
                float x[16];
#pragma unroll
                for (int ksr = 0; ksr < 16; ++ksr)
                    x[ksr] = ldf(&part[(size_t)ksr * (NB * NTOT) + gtid]);
                float s = 0.f;
#pragma unroll
                for (int ksr = 0; ksr < 16; ++ksr) s += x[ksr];
                float sq = s * s;
                sq += __shfl_xor(sq, 1);      // sum over u (aligned 16-lane groups)
                sq += __shfl_xor(sq, 2);
                sq += __shfl_xor(sq, 4);
                sq += __shfl_xor(sq, 8);
                float vv = s * (sq / ((1.f + sq) * sqrtf(sq + 1e-9f)));
                if (t == 2) {
                    vout[gtid] = vv;          // only final v is observable
                } else {
                    int n = gtid % NTOT, b = gtid / NTOT;
                    stf(&vTf[(size_t)n * 256 + b], vv);
                }
            }
        }

        if (t < 2) {
            gbar(bar, ++ph);
            // ---------------- delta: 2880 virtual waves over 2048 real -----
            for (int g = blk * 4 + wid; g < 2880; g += GRID * 4) {
                const int mt   = g % 576;
                const int ntp  = g / 576;     // 0..4 -> nt = ntp*2, ntp*2+1
                const int l15  = lane & 15;
                const int quad = lane >> 4;
                const int koff = quad * 8;
                const int nt0  = ntp * 2;

                const unsigned short* ap = inpT + (size_t)(mt * 16 + l15) * 256 + koff;
                const float* bp0 = vTf + (size_t)(nt0 * 16 + l15) * 256 + koff;
                const float* bp1 = bp0 + 16 * 256;

                f32x4 acc0 = {0.f, 0.f, 0.f, 0.f};
                f32x4 acc1 = {0.f, 0.f, 0.f, 0.f};
#pragma unroll
                for (int kk = 0; kk < 8; ++kk) {
                    short8 av = *(const short8*)(ap + kk * 32);  // plain: immutable
                    short8 b0 = ld_v8(bp0 + kk * 32);            // sc1 + cvt (bit-exact)
                    short8 b1 = ld_v8(bp1 + kk * 32);
                    acc0 = __builtin_amdgcn_mfma_f32_16x16x32_bf16(av, b0, acc0, 0, 0, 0);
                    acc1 = __builtin_amdgcn_mfma_f32_16x16x32_bf16(av, b1, acc1, 0, 0, 0);
                }

                // lane holds G[m=quad*4+r][n=l15]; m -> i_loc = quad>>1, k=(quad&1)*4+r
                const int i = mt * 2 + (quad >> 1);
                const float* wr0 = W + (((size_t)i * OC + nt0) * OU + l15) * IK + (quad & 1) * 4;
                float4 wf0 = *(const float4*)wr0;
                float4 wf1 = *(const float4*)(wr0 + OU * IK);   // nt0+1 adjacent in W
                float w0 = wf0.x * acc0[0] + wf0.y * acc0[1] + wf0.z * acc0[2] + wf0.w * acc0[3];
                float w1 = wf1.x * acc1[0] + wf1.y * acc1[1] + wf1.z * acc1[2] + wf1.w * acc1[3];

#pragma unroll
                for (int d = 0; d < 5; ++d) {
                    int m = (d == 0) ? 16 : (1 << (d - 1));   // 16, 1, 2, 4, 8
                    w0 += __shfl_xor(w0, m);
                    w1 += __shfl_xor(w1, m);
                }

                if ((lane & 31) == 0) {       // one writer per (i,o), no atomics
                    float* b0p = &blog[(size_t)i * OC + nt0];
                    stf(b0p,     ldf(b0p)     + w0 * (1.0f / NB));
                    stf(b0p + 1, ldf(b0p + 1) + w1 * (1.0f / NB));
                }
            }
            gbar(bar, ++ph);
        }
    }
}

// ===================== fallback: proven multi-kernel path (127.9us) =====

__global__ __launch_bounds__(256) void prep_kernel(
    const float* __restrict__ inp,
    float* __restrict__ blog,
    unsigned short* __restrict__ inpb,
    unsigned short* __restrict__ inpT)
{
    const int kt  = blockIdx.x;
    const int bt  = blockIdx.y;
    const int tid = threadIdx.x;
    {
        int bid = blockIdx.y * 144 + blockIdx.x;
        if (bid < 45) blog[bid * 256 + tid] = 0.f;
    }
    __shared__ unsigned short sh[64][65];
#pragma unroll
    for (int j = 0; j < 4; ++j) {
        int q = j * 256 + tid;
        int b_loc = q >> 4;
        int kq = (q & 15) * 4;
        float4 g = *(const float4*)&inp[(size_t)(bt * 64 + b_loc) * KTOT + kt * 64 + kq];
        unsigned short h0 = f2bf(g.x), h1 = f2bf(g.y), h2 = f2bf(g.z), h3 = f2bf(g.w);
        sh[kq][b_loc] = h0; sh[kq + 1][b_loc] = h1;
        sh[kq + 2][b_loc] = h2; sh[kq + 3][b_loc] = h3;
        short4 pk = { (short)h0, (short)h1, (short)h2, (short)h3 };
        *(short4*)&inpb[(size_t)(bt * 64 + b_loc) * KTOT + kt * 64 + kq] = pk;
    }
    __syncthreads();
#pragma unroll
    for (int j = 0; j < 4; ++j) {
        int q = j * 256 + tid;
        int k_loc = q >> 4;
        int b4 = (q & 15) * 4;
        short4 pk = { (short)sh[k_loc][b4],     (short)sh[k_loc][b4 + 1],
                      (short)sh[k_loc][b4 + 2], (short)sh[k_loc][b4 + 3] };
        *(short4*)&inpT[(size_t)(kt * 64 + k_loc) * 256 + bt * 64 + b4] = pk;
    }
}

__global__ __launch_bounds__(256) void spass_kernel(
    const unsigned short* __restrict__ inpb,
    const float* __restrict__ W,
    const float* __restrict__ blog,
    float* __restrict__ part)
{
    const int bid  = blockIdx.x;
    const int nt   = bid % 10;
    const int ks   = (bid / 10) % 16;
    const int mtg  = bid / 160;
    const int tid  = threadIdx.x;
    const int w    = tid >> 6;
    const int lane = tid & 63;
    const int l15  = lane & 15;
    const int koff = (lane >> 4) * 8;
    const int k0   = ks * 576;
    const int i0   = ks * 72;
    const int mt   = mtg * 4 + w;

    __shared__ unsigned short Bl[16 * BLP];
    __shared__ float c_loc[72];

    if (tid < 72) {
        const float* br = &blog[(size_t)(i0 + tid) * OC];
        float x[OC], m = -1e30f;
#pragma unroll
        for (int o = 0; o < OC; ++o) { x[o] = br[o]; m = fmaxf(m, x[o]); }
        float ssum = 0.f;
#pragma unroll
        for (int o = 0; o < OC; ++o) ssum += expf(x[o] - m);
        c_loc[tid] = expf(x[nt] - m) / ssum;
    }
    __syncthreads();
#pragma unroll
    for (int jj = 0; jj < 5; ++jj) {
        int q = jj * 256 + tid;
        if (q < 1152) {
            int i_loc = q >> 4, u = q & 15;
            const float* wr = W + (((size_t)(i0 + i_loc) * OC + nt) * OU + u) * IK;
            float4 a = *(const float4*)wr;
            float4 b = *(const float4*)(wr + 4);
            float cc = c_loc[i_loc];
            union { short8 v; unsigned short us[8]; } pk;
            pk.us[0] = f2bf(cc * a.x); pk.us[1] = f2bf(cc * a.y);
            pk.us[2] = f2bf(cc * a.z); pk.us[3] = f2bf(cc * a.w);
            pk.us[4] = f2bf(cc * b.x); pk.us[5] = f2bf(cc * b.y);
            pk.us[6] = f2bf(cc * b.z); pk.us[7] = f2bf(cc * b.w);
            *(short8*)&Bl[u * BLP + i_loc * 8] = pk.v;
        }
    }
    __syncthreads();

    const unsigned short* ap  = inpb + (size_t)(mt * 16 + l15) * KTOT + k0 + koff;
    const unsigned short* bls = &Bl[l15 * BLP + koff];
    f32x4 acc = {0.f, 0.f, 0.f, 0.f};
#pragma unroll
    for (int kk = 0; kk < 18; ++kk) {
        short8 av = *(const short8*)(ap + kk * 32);
        short8 bv = *(const short8*)(bls + kk * 32);
        acc = __builtin_amdgcn_mfma_f32_16x16x32_bf16(av, bv, acc, 0, 0, 0);
    }
    float* pp = part + ((size_t)ks * NB + mt * 16 + (lane >> 4) * 4) * NTOT + nt * 16 + l15;
#pragma unroll
    for (int r = 0; r < 4; ++r)
        pp[(size_t)r * NTOT] = acc[r];
}

__global__ __launch_bounds__(256) void reduce_squash_kernel(
    const float* __restrict__ part, float* __restrict__ vout,
    unsigned short* __restrict__ vT)
{
    const int tid = threadIdx.x;
    const int el  = tid & 31;
    const int kl  = tid >> 5;
    const int e   = blockIdx.x * 32 + el;

    float a = part[(size_t)(kl * 2) * (NB * NTOT) + e]
            + part[(size_t)(kl * 2 + 1) * (NB * NTOT) + e];

    __shared__ float red[8][36];
    red[kl][el] = a;
    __syncthreads();

    if (tid < 32) {
        float s = ((red[0][el] + red[1][el]) + (red[2][el] + red[3][el]))
                + ((red[4][el] + red[5][el]) + (red[6][el] + red[7][el]));
        float sq = s * s;
        sq += __shfl_xor(sq, 1);
        sq += __shfl_xor(sq, 2);
        sq += __shfl_xor(sq, 4);
        sq += __shfl_xor(sq, 8);
        float vv = s * (sq / ((1.f + sq) * sqrtf(sq + 1e-9f)));
        vout[e] = vv;
        int n = e % NTOT, b = e / NTOT;
        vT[(size_t)n * 256 + b] = f2bf(vv);
    }
}

__global__ __launch_bounds__(256) void delta_kernel(
    const unsigned short* __restrict__ inpT,
    const unsigned short* __restrict__ vT,
    const float* __restrict__ W,
    float* __restrict__ blog)
{
    const int g    = blockIdx.x * 4 + (threadIdx.x >> 6);
    const int lane = threadIdx.x & 63;
    const int mt   = g % 576;
    const int ntp  = g / 576;
    const int l15  = lane & 15;
    const int quad = lane >> 4;
    const int koff = quad * 8;
    const int nt0  = ntp * 2;

    const unsigned short* ap  = inpT + (size_t)(mt * 16 + l15) * 256 + koff;
    const unsigned short* bp0 = vT   + (size_t)(nt0 * 16 + l15) * 256 + koff;
    const unsigned short* bp1 = bp0 + 16 * 256;

    f32x4 acc0 = {0.f, 0.f, 0.f, 0.f};
    f32x4 acc1 = {0.f, 0.f, 0.f, 0.f};
#pragma unroll
    for (int kk = 0; kk < 8; ++kk) {
        short8 av = *(const short8*)(ap  + kk * 32);
        short8 b0 = *(const short8*)(bp0 + kk * 32);
        short8 b1 = *(const short8*)(bp1 + kk * 32);
        acc0 = __builtin_amdgcn_mfma_f32_16x16x32_bf16(av, b0, acc0, 0, 0, 0);
        acc1 = __builtin_amdgcn_mfma_f32_16x16x32_bf16(av, b1, acc1, 0, 0, 0);
    }
    const int i = mt * 2 + (quad >> 1);
    const float* wr0 = W + (((size_t)i * OC + nt0) * OU + l15) * IK + (quad & 1) * 4;
    float4 wf0 = *(const float4*)wr0;
    float4 wf1 = *(const float4*)(wr0 + OU * IK);
    float w0 = wf0.x * acc0[0] + wf0.y * acc0[1] + wf0.z * acc0[2] + wf0.w * acc0[3];
    float w1 = wf1.x * acc1[0] + wf1.y * acc1[1] + wf1.z * acc1[2] + wf1.w * acc1[3];
#pragma unroll
    for (int d = 0; d < 5; ++d) {
        int m = (d == 0) ? 16 : (1 << (d - 1));
        w0 += __shfl_xor(w0, m);
        w1 += __shfl_xor(w1, m);
    }
    if ((lane & 31) == 0) {
        blog[(size_t)i * OC + nt0]     += w0 * (1.0f / NB);
        blog[(size_t)i * OC + nt0 + 1] += w1 * (1.0f / NB);
    }
}

extern "C" void kernel_launch(void* const* d_in, const int* in_sizes, int n_in,
                              void* d_out, int out_size, void* d_ws, size_t ws_size,
                              hipStream_t stream) {
    const float* inp = (const float*)d_in[0];   // [256][1152][8]
    const float* W   = (const float*)d_in[1];   // [1152][10][16][8]
    float* vout = (float*)d_out;                // [256][10][16]

    float* blog = (float*)d_ws;                              // 11,520 f
    float* part = blog + IC * OC;                            // 655,360 f
    unsigned short* inpb = (unsigned short*)(part + (size_t)S_KS * NB * NTOT);
    unsigned short* inpT = inpb + (size_t)NB * KTOT;         // 2,359,296 u16
    float* vTf = (float*)(inpT + (size_t)KTOT * 256);        // 40,960 f32
    // barrier counters: 128B-aligned after vTf
    size_t bar_off = (((size_t)(vTf + NTOT * 256) - (size_t)d_ws) + 127) & ~(size_t)127;
    u32* bar = (u32*)((char*)d_ws + bar_off);

    hipMemsetAsync(bar, 0, 4096, stream);       // reset barrier state each replay

    void* args[] = { (void*)&inp, (void*)&W, (void*)&blog, (void*)&part,
                     (void*)&inpb, (void*)&inpT, (void*)&vTf, (void*)&vout,
                     (void*)&bar };
    hipError_t err = hipLaunchCooperativeKernel(fused_kernel, dim3(GRID), dim3(256),
                                                args, 0u, stream);
    if (err != hipSuccess) {
        // graceful fallback: the verified multi-kernel path
        unsigned short* vT = (unsigned short*)vTf;   // reuse region as bf16 vT
        prep_kernel<<<dim3(144, 4), dim3(256), 0, stream>>>(inp, blog, inpb, inpT);
        for (int t = 0; t < 3; ++t) {
            spass_kernel<<<dim3(640), dim3(256), 0, stream>>>(inpb, W, blog, part);
            reduce_squash_kernel<<<dim3(NB * NTOT / 32), dim3(256), 0, stream>>>(part, vout, vT);
            if (t < 2)
                delta_kernel<<<dim3(720), dim3(256), 0, stream>>>(inpT, vT, W, blog);
        }
    }
}